// Round 16
// baseline (339.794 us; speedup 1.0000x reference)
//
#include <hip/hip_runtime.h>

typedef _Float16 f16x8 __attribute__((ext_vector_type(8)));
typedef __fp16 fp16x2 __attribute__((ext_vector_type(2)));
typedef __attribute__((ext_vector_type(4))) float f32x4;

#define CC 256
#define SS 1024
#define KK 4
#define XR 6
#define XC 34
#define NCELL (XR * XC)  // 204

__device__ __forceinline__ unsigned int pk2h(float a, float b) {
  fp16x2 h = __builtin_amdgcn_cvt_pkrtz(a, b);
  return __builtin_bit_cast(unsigned int, h);
}

__device__ __forceinline__ void gll16(const void* g, void* l) {
  __builtin_amdgcn_global_load_lds((const __attribute__((address_space(1))) void*)g,
                                   (__attribute__((address_space(3))) void*)l, 16, 0, 0);
}

#define S_VMCNT0 asm volatile("s_waitcnt vmcnt(0)" ::: "memory")
#define S_LGKM0 asm volatile("s_waitcnt lgkmcnt(0)" ::: "memory")
#define SCHED0 __builtin_amdgcn_sched_barrier(0)

// qk[c][n] = sum_d Wk[c, n*64+d] * q[n, d]
__global__ void qk_kernel(const float* __restrict__ Wk, const float* __restrict__ q,
                          float* __restrict__ qk) {
  int t = blockIdx.x * blockDim.x + threadIdx.x;
  if (t >= CC * 2) return;
  int c = t >> 1, n = t & 1;
  float s = 0.f;
  for (int d = 0; d < 64; ++d) s += Wk[c * 128 + n * 64 + d] * q[n * 64 + d];
  qk[c * 2 + n] = s;
}

// One pass over x per step: per (b, 64-pixel chunk) compute raw scores,
// chunk-local softmax stats (m, Z) and partial attn-weighted sums xa.
// part layout per (b,ch): [0]=m0 [1]=m1 [2]=Z0 [3]=Z1 [4..259]=xa0 [260..515]=xa1 (stride 520)
__global__ void poolpart_kernel(const float* __restrict__ x, const float* __restrict__ qk,
                                float* __restrict__ scores, float* __restrict__ part) {
  __shared__ float xs[64][260];
  __shared__ float ds[2][64];
  int ch = blockIdx.x, b = blockIdx.y, tid = threadIdx.x;
  int s0 = ch * 64;
  const float* xb = x + ((size_t)b * 1024 + s0) * 256;
  for (int i = tid; i < 4096; i += 256) {
    int r = i >> 6, c4 = (i & 63) << 2;
    *(float4*)(&xs[r][c4]) = *(const float4*)(xb + (size_t)r * 256 + c4);
  }
  __syncthreads();
  int lane = tid & 63, wv = tid >> 6;
  float q0[4], q1[4];
#pragma unroll
  for (int j = 0; j < 4; ++j) {
    q0[j] = qk[(lane + j * 64) * 2 + 0];
    q1[j] = qk[(lane + j * 64) * 2 + 1];
  }
  for (int p = 0; p < 16; ++p) {
    int s = wv * 16 + p;
    float d0 = 0.f, d1 = 0.f;
#pragma unroll
    for (int j = 0; j < 4; ++j) {
      float xv = xs[s][lane + j * 64];
      d0 += xv * q0[j];
      d1 += xv * q1[j];
    }
#pragma unroll
    for (int sh = 32; sh >= 1; sh >>= 1) {
      d0 += __shfl_xor(d0, sh, 64);
      d1 += __shfl_xor(d1, sh, 64);
    }
    if (lane == 0) {
      ds[0][s] = d0 * 0.125f;
      ds[1][s] = d1 * 0.125f;
      scores[((size_t)b * 2 + 0) * 1024 + s0 + s] = d0 * 0.125f;
      scores[((size_t)b * 2 + 1) * 1024 + s0 + s] = d1 * 0.125f;
    }
  }
  __syncthreads();
  if (wv < 2) {
    float v = ds[wv][lane];
    float m = v;
#pragma unroll
    for (int sh = 32; sh >= 1; sh >>= 1) m = fmaxf(m, __shfl_xor(m, sh, 64));
    float e = expf(v - m);
    float Z = e;
#pragma unroll
    for (int sh = 32; sh >= 1; sh >>= 1) Z += __shfl_xor(Z, sh, 64);
    ds[wv][lane] = e;
    if (lane == 0) {
      float* o = part + ((size_t)(b * 16 + ch)) * 520;
      o[wv] = m;
      o[2 + wv] = Z;
    }
  }
  __syncthreads();
  float a0 = 0.f, a1 = 0.f;
  for (int s = 0; s < 64; ++s) {
    float xv = xs[s][tid];
    a0 += ds[0][s] * xv;
    a1 += ds[1][s] * xv;
  }
  float* o = part + ((size_t)(b * 16 + ch)) * 520;
  o[4 + tid] = a0;
  o[4 + 256 + tid] = a1;
}

// Fused routing + per-batch expert-weight combine. Grid (72, 32): every block
// redundantly computes its batch's routing (deterministic, bit-identical
// across blocks); tile==0 publishes selE/selW/allowed_out; tiles 0..7 write
// rowscale; then each block combines its weight tile -> f16 Wc_h.
__global__ void routecombine_kernel(
    const float* __restrict__ part, const float* __restrict__ scores,
    const float* __restrict__ Wv, const float* __restrict__ Wmlp,
    const float* __restrict__ alpha, const float* __restrict__ We,
    const float* __restrict__ allowed_in, float* __restrict__ allowed_out,
    float* __restrict__ rowscale, int* __restrict__ selE, float* __restrict__ selW,
    unsigned short* __restrict__ Wc_h, int step) {
  __shared__ float ts[32][257];
  __shared__ float xs[512];
  __shared__ float pooled[128];
  __shared__ float lg[4];
  __shared__ float Msh[2], iZsh[2];
  __shared__ float cs[2][16];
  __shared__ int sel_sh[2];
  __shared__ float sw_sh[2];
  int tile = blockIdx.x;  // 0..71 = tap*8+kc
  int b = blockIdx.y;
  int tid = threadIdx.x;

  // ---- routing (redundant per block, deterministic) ----
  if (tid < 2) {
    float m = -1e30f;
    for (int ch = 0; ch < 16; ++ch)
      m = fmaxf(m, part[((size_t)(b * 16 + ch)) * 520 + tid]);
    float z = 0.f;
    for (int ch = 0; ch < 16; ++ch) {
      const float* p = part + ((size_t)(b * 16 + ch)) * 520;
      z += expf(p[tid] - m) * p[2 + tid];
    }
    Msh[tid] = m;
    iZsh[tid] = 1.f / z;
  }
  __syncthreads();
  if (tid < 32) {
    int n = tid >> 4, ch = tid & 15;
    cs[n][ch] = expf(part[((size_t)(b * 16 + ch)) * 520 + n] - Msh[n]);
  }
  __syncthreads();
#pragma unroll
  for (int i = 0; i < 2; ++i) {
    int id = tid + i * 256;
    int n = id >> 8, c = id & 255;
    float s = 0.f;
    for (int ch = 0; ch < 16; ++ch)
      s += cs[n][ch] * part[((size_t)(b * 16 + ch)) * 520 + 4 + n * 256 + c];
    xs[id] = s * iZsh[n];
  }
  __syncthreads();
  if (tid < 128) {
    int n = tid >> 6;
    float s = 0.f;
    const float* xr = xs + n * 256;
    for (int c = 0; c < 256; ++c) s += xr[c] * Wv[(size_t)c * 128 + tid];
    pooled[tid] = s;
  }
  __syncthreads();
  if (tid < 4) {
    float s = 0.f;
    for (int d = 0; d < 128; ++d) s += pooled[d] * Wmlp[d * 4 + tid];
    lg[tid] = s;
  }
  __syncthreads();
  if (tid == 0) {
    float al[KK];
    if (step == 0) { for (int k = 0; k < KK; ++k) al[k] = 1.f; }
    else           { for (int k = 0; k < KK; ++k) al[k] = allowed_in[b * KK + k]; }
    float ml[KK];
    for (int k = 0; k < KK; ++k)
      ml[k] = (al[k] > 0.5f) ? lg[k] * (1.f / 1.5f) : (-1e9f) * (1.f / 1.5f);
    float m = ml[0];
    for (int k = 1; k < KK; ++k) m = fmaxf(m, ml[k]);
    float e[KK], ssum = 0.f;
    for (int k = 0; k < KK; ++k) { e[k] = expf(ml[k] - m); ssum += e[k]; }
    float w[KK];
    for (int k = 0; k < KK; ++k) w[k] = e[k] / ssum;
    int i0 = 0;
    for (int k = 1; k < KK; ++k) if (w[k] > w[i0]) i0 = k;
    int i1 = -1;
    for (int k = 0; k < KK; ++k) {
      if (k == i0) continue;
      if (i1 < 0 || w[k] > w[i1]) i1 = k;
    }
    float denom = w[i0] + w[i1] + 1e-9f;
    sel_sh[0] = i0;
    sel_sh[1] = i1;
    sw_sh[0] = w[i0] / denom;
    sw_sh[1] = w[i1] / denom;
    if (tile == 0) {
      selE[b * 2 + 0] = i0;
      selE[b * 2 + 1] = i1;
      selW[b * 2 + 0] = sw_sh[0];
      selW[b * 2 + 1] = sw_sh[1];
      if (i0 != KK - 1) al[i0] = fminf(fmaxf(al[i0] - 1.f, 0.f), 1.f);
      al[KK - 1] = fmaxf(al[KK - 1], 1.f);
      for (int k = 0; k < KK; ++k) allowed_out[b * KK + k] = al[k];
    }
  }
  // rowscale: tiles 0..7 each cover 128 pixels
  if (tile < 8 && tid < 128) {
    float M0 = Msh[0], M1 = Msh[1], iZ0 = iZsh[0], iZ1 = iZsh[1];
    float alv = alpha[0];
    float a = (alv > 20.f) ? alv : log1pf(expf(alv));
    float k = 0.5f * 1024.f * a;
    int i = tile * 128 + tid;
    float d0 = scores[((size_t)b * 2 + 0) * 1024 + i];
    float d1 = scores[((size_t)b * 2 + 1) * 1024 + i];
    rowscale[(size_t)b * 1024 + i] = 1.f + k * (expf(d0 - M0) * iZ0 + expf(d1 - M1) * iZ1);
  }
  __syncthreads();

  // ---- weight combine for this tile ----
  int e0 = sel_sh[0], e1 = sel_sh[1];
  float w0 = sw_sh[0], w1 = sw_sh[1];
  int tap = tile >> 3, kc = tile & 7;
  int co = tid;
  const float* s0 = We + (size_t)(e0 * 9 + tap) * 65536 + (size_t)(kc * 32) * 256 + co;
  const float* s1 = We + (size_t)(e1 * 9 + tap) * 65536 + (size_t)(kc * 32) * 256 + co;
  for (int ci = 0; ci < 32; ++ci)
    ts[ci][co] = w0 * s0[(size_t)ci * 256] + w1 * s1[(size_t)ci * 256];
  __syncthreads();
  unsigned int hw[16];
#pragma unroll
  for (int k2 = 0; k2 < 16; ++k2) hw[k2] = pk2h(ts[k2 * 2][co], ts[k2 * 2 + 1][co]);
  size_t base = ((size_t)b * 72 + tile) * 8192 + (size_t)co * 32;
#pragma unroll
  for (int j = 0; j < 4; ++j)
    *(uint4*)(Wc_h + base + j * 8) = make_uint4(hw[j * 4], hw[j * 4 + 1], hw[j * 4 + 2], hw[j * 4 + 3]);
}

// MFMA implicit-GEMM conv, single-f16 (proven config). Block = 256 thr
// (4 waves, 2m x 2n), M=128 pixels, N=128 cos; wave tile 64x64. x (f16)
// double-buffered in XOR-swizzled LDS; w via global_load_lds into 3-tile
// GROUP buffers (double-buffered). One vmcnt(0)+s_barrier per 3-tap group;
// stage_x for kc+1 overlapped under kc's first group. rowscale cached in
// LDS; f16 conversion via v_cvt_pkrtz.
__global__ __launch_bounds__(256, 2) void conv_kernel(
    const float* __restrict__ xin, const float* __restrict__ rowscale,
    const unsigned short* __restrict__ Wc_h,
    const float* __restrict__ be,
    const int* __restrict__ selE, const float* __restrict__ selW,
    float* __restrict__ out) {
  __shared__ __align__(16) unsigned char xsB[2][NCELL * 64];  // 2 x 13056
  __shared__ __align__(16) unsigned char BsB[2][3 * 8192];    // 2 x 24576
  __shared__ float rs_lds[NCELL];                             // 816 B

  int bid = blockIdx.x;
  int xcd = bid & 7, t2b = bid >> 3;
  int mt = t2b & 7, gs = t2b >> 3;
  int g = gs * 8 + xcd;           // (b,nt) group; its 8 mt-blocks share one XCD
  int b = g >> 1, nt = g & 1;
  int h0 = mt * 4;
  int tid = threadIdx.x;
  int lane = tid & 63, wid = tid >> 6;
  int wm = wid >> 1, wn = wid & 1;
  int l15 = lane & 15, kl = lane >> 4;

  int e0 = selE[b * 2], e1 = selE[b * 2 + 1];
  float w0 = selW[b * 2], w1 = selW[b * 2 + 1];

  int cellb[4];
#pragma unroll
  for (int mf = 0; mf < 4; ++mf) {
    int p0 = wm * 64 + mf * 16;
    cellb[mf] = (p0 >> 5) * XC + (p0 & 31) + l15;
  }
  int bbyte[4];
#pragma unroll
  for (int nf = 0; nf < 4; ++nf) {
    int co = wn * 64 + nf * 16 + l15;
    bbyte[nf] = (co * 64 + kl * 16) ^ ((co & 7) << 4);
  }
  // gll source pre-swizzle: dest oh -> (co, s) with LDS[(co*64+s*16)^((co&7)<<4)] = W[co][s*8..]
  int elemoff[2];
#pragma unroll
  for (int j = 0; j < 2; ++j) {
    int oh = wid * 2048 + j * 1024 + lane * 16;
    int co = ((oh >> 7) << 1) | (((oh >> 6) ^ (oh >> 8)) & 1);
    int s = ((oh >> 4) & 3) ^ (co & 3);
    elemoff[j] = (nt * 128 + co) * 32 + s * 8;
  }
  const unsigned short* WH = Wc_h + (size_t)b * 72 * 8192;

  float bias[4];
#pragma unroll
  for (int nf = 0; nf < 4; ++nf) {
    int con = nt * 128 + wn * 64 + nf * 16 + l15;
    bias[nf] = w0 * be[e0 * 256 + con] + w1 * be[e1 * 256 + con];
  }

  f32x4 acc[4][4];
#pragma unroll
  for (int mf = 0; mf < 4; ++mf)
#pragma unroll
    for (int nf = 0; nf < 4; ++nf) acc[mf][nf] = (f32x4){0.f, 0.f, 0.f, 0.f};

  // fill rowscale cache (kc-invariant)
  for (int i = tid; i < NCELL; i += 256) {
    int r = i / XC, c = i - r * XC;
    int gr = h0 - 1 + r, gc = c - 1;
    float v = 0.f;
    if (gr >= 0 && gr < 32 && gc >= 0 && gc < 32)
      v = rowscale[(size_t)b * 1024 + gr * 32 + gc];
    rs_lds[i] = v;
  }

  // stage x (f16 pkrtz, x_mod fused) for K-chunk kcc into xsB[kcc&1]
  auto stage_x = [&](int kcc) {
    unsigned char* xd = xsB[kcc & 1];
    for (int idx = tid; idx < NCELL * 2; idx += 256) {
      int hk = (idx >= NCELL) ? 1 : 0;
      int cell = idx - hk * NCELL;
      int r = cell / XC, c = cell - r * XC;
      int gr = h0 - 1 + r, gc = c - 1;
      uint4 pk = make_uint4(0, 0, 0, 0), pk2 = make_uint4(0, 0, 0, 0);
      if (gr >= 0 && gr < 32 && gc >= 0 && gc < 32) {
        const float* src = xin + (((size_t)b * 32 + gr) * 32 + gc) * 256 + kcc * 32 + hk * 16;
        float sc = rs_lds[cell];
        float xv[16];
        *(float4*)(xv + 0) = *(const float4*)(src + 0);
        *(float4*)(xv + 4) = *(const float4*)(src + 4);
        *(float4*)(xv + 8) = *(const float4*)(src + 8);
        *(float4*)(xv + 12) = *(const float4*)(src + 12);
        unsigned int u[8];
#pragma unroll
        for (int e2 = 0; e2 < 8; ++e2)
          u[e2] = pk2h(xv[e2 * 2] * sc, xv[e2 * 2 + 1] * sc);
        pk = make_uint4(u[0], u[1], u[2], u[3]);
        pk2 = make_uint4(u[4], u[5], u[6], u[7]);
      }
      int sx = (cell & 7) << 4;
      int b0 = (cell * 64 + hk * 32) ^ sx;
      int b1 = (cell * 64 + hk * 32 + 16) ^ sx;
      *(uint4*)(xd + b0) = pk;
      *(uint4*)(xd + b1) = pk2;
    }
  };

  auto issue_group = [&](int kcA, int subBase, int buf) {
#pragma unroll
    for (int t = 0; t < 3; ++t) {
      const unsigned short* sp = WH + (size_t)((subBase + t) * 8 + kcA) * 8192;
      char* lb = (char*)&BsB[buf][t * 8192] + wid * 2048;
      gll16(sp + elemoff[0], lb);
      gll16(sp + elemoff[1], lb + 1024);
    }
    SCHED0;
  };

  auto do_tap = [&](int tap, int tIdx, const unsigned char* xsCur, int buf) {
    const int dy = (tap >= 6) ? 2 : ((tap >= 3) ? 1 : 0);
    const int dx = tap - dy * 3;
    const int dcell = dy * XC + dx;
    const unsigned char* bp = &BsB[buf][tIdx * 8192];
    f16x8 af[4], bf[4];
#pragma unroll
    for (int mf = 0; mf < 4; ++mf) {
      int cell = cellb[mf] + dcell;
      int abyte = (cell * 64 + kl * 16) ^ ((cell & 7) << 4);
      af[mf] = *(const f16x8*)(xsCur + abyte);
    }
#pragma unroll
    for (int nf = 0; nf < 4; ++nf) bf[nf] = *(const f16x8*)(bp + bbyte[nf]);
    __builtin_amdgcn_s_setprio(1);
#pragma unroll
    for (int mf = 0; mf < 4; ++mf)
#pragma unroll
      for (int nf = 0; nf < 4; ++nf)
        acc[mf][nf] = __builtin_amdgcn_mfma_f32_16x16x32_f16(af[mf], bf[nf], acc[mf][nf], 0, 0, 0);
    __builtin_amdgcn_s_setprio(0);
  };

  // ---- prologue ----
  issue_group(0, 0, 0);
  __syncthreads();   // rs_lds visible to all before stage_x uses it
  stage_x(0);
  S_VMCNT0;
  S_LGKM0;
  SCHED0;
  __builtin_amdgcn_s_barrier();

#pragma unroll 1
  for (int kc = 0; kc < 8; ++kc) {
    const unsigned char* xsCur = xsB[kc & 1];
    const int bX = kc & 1;
    // group 0: taps 0-2 from BsB[bX]; overlap next-kc x staging
    if (kc < 7) stage_x(kc + 1);
    issue_group(kc, 3, bX ^ 1);
    do_tap(0, 0, xsCur, bX);
    do_tap(1, 1, xsCur, bX);
    do_tap(2, 2, xsCur, bX);
    S_VMCNT0;
    SCHED0;
    __builtin_amdgcn_s_barrier();
    // group 1: taps 3-5 from BsB[bX^1]
    issue_group(kc, 6, bX);
    do_tap(3, 0, xsCur, bX ^ 1);
    do_tap(4, 1, xsCur, bX ^ 1);
    do_tap(5, 2, xsCur, bX ^ 1);
    S_VMCNT0;
    SCHED0;
    __builtin_amdgcn_s_barrier();
    // group 2: taps 6-8 from BsB[bX]
    if (kc < 7) issue_group(kc + 1, 0, bX ^ 1);
    do_tap(6, 0, xsCur, bX);
    do_tap(7, 1, xsCur, bX);
    do_tap(8, 2, xsCur, bX);
    if (kc < 7) { S_LGKM0; }  // xs writes for kc+1 (issued in group 0) drained
    S_VMCNT0;
    SCHED0;
    __builtin_amdgcn_s_barrier();
  }

#pragma unroll
  for (int mf = 0; mf < 4; ++mf) {
    int p0 = wm * 64 + mf * 16;
    int pr = p0 >> 5, pc = p0 & 31;
    size_t rowbase = ((size_t)b * 32 + h0 + pr) * 32;
#pragma unroll
    for (int nf = 0; nf < 4; ++nf) {
      int co = nt * 128 + wn * 64 + nf * 16 + l15;
#pragma unroll
      for (int rr = 0; rr < 4; ++rr) {
        int col = pc + kl * 4 + rr;
        out[(rowbase + col) * 256 + co] = acc[mf][nf][rr] + bias[nf];
      }
    }
  }
}

extern "C" void kernel_launch(void* const* d_in, const int* in_sizes, int n_in,
                              void* d_out, int out_size, void* d_ws, size_t ws_size,
                              hipStream_t stream) {
  const float* x_in  = (const float*)d_in[0];
  const float* q     = (const float*)d_in[1];
  const float* Wk    = (const float*)d_in[2];
  const float* Wv    = (const float*)d_in[3];
  const float* Wmlp  = (const float*)d_in[4];
  const float* alpha = (const float*)d_in[5];
  const float* We    = (const float*)d_in[6];
  const float* be    = (const float*)d_in[7];
  float* out = (float*)d_out;
  float* ws = (float*)d_ws;

  float* qk       = ws;                  // 512
  float* scores   = qk + 512;            // 65536
  float* rowscale = scores + 65536;      // 32768
  float* part     = rowscale + 32768;    // 32*16*520 = 266240
  float* alwA     = part + 266240;       // 128
  float* alwB     = alwA + 128;          // 128
  float* selW     = alwB + 128;          // 64
  int*   selE     = (int*)(selW + 64);   // 64
  float* xbuf     = selW + 128;          // 8388608 floats
  unsigned short* Wc_h = (unsigned short*)(xbuf + 8388608);  // 18,874,368 ushorts

  qk_kernel<<<2, 256, 0, stream>>>(Wk, q, qk);

  const float* step_in[3] = {x_in, out, xbuf};
  float* step_out[3] = {out, xbuf, out};
  float* alw[2] = {alwA, alwB};

  for (int t = 0; t < 3; ++t) {
    const float* xc = step_in[t];
    poolpart_kernel<<<dim3(16, 32), 256, 0, stream>>>(xc, qk, scores, part);
    routecombine_kernel<<<dim3(72, 32), 256, 0, stream>>>(
        part, scores, Wv, Wmlp, alpha, We, alw[t & 1], alw[(t + 1) & 1],
        rowscale, selE, selW, Wc_h, t);
    conv_kernel<<<512, 256, 0, stream>>>(xc, rowscale, Wc_h, be, selE, selW, step_out[t]);
  }
}

// Round 17
// 294.430 us; speedup vs baseline: 1.1541x; 1.1541x over previous
//
#include <hip/hip_runtime.h>

typedef _Float16 f16x8 __attribute__((ext_vector_type(8)));
typedef __fp16 fp16x2 __attribute__((ext_vector_type(2)));
typedef __attribute__((ext_vector_type(4))) float f32x4;

#define CC 256
#define SS 1024
#define KK 4
#define XR 6
#define XC 34
#define NCELL (XR * XC)  // 204

__device__ __forceinline__ unsigned int pk2h(float a, float b) {
  fp16x2 h = __builtin_amdgcn_cvt_pkrtz(a, b);
  return __builtin_bit_cast(unsigned int, h);
}

__device__ __forceinline__ void gll16(const void* g, void* l) {
  __builtin_amdgcn_global_load_lds((const __attribute__((address_space(1))) void*)g,
                                   (__attribute__((address_space(3))) void*)l, 16, 0, 0);
}

#define S_VMCNT0 asm volatile("s_waitcnt vmcnt(0)" ::: "memory")
#define S_LGKM0 asm volatile("s_waitcnt lgkmcnt(0)" ::: "memory")
#define SCHED0 __builtin_amdgcn_sched_barrier(0)

// qk[c][n] = sum_d Wk[c, n*64+d] * q[n, d]
__global__ void qk_kernel(const float* __restrict__ Wk, const float* __restrict__ q,
                          float* __restrict__ qk) {
  int t = blockIdx.x * blockDim.x + threadIdx.x;
  if (t >= CC * 2) return;
  int c = t >> 1, n = t & 1;
  float s = 0.f;
  for (int d = 0; d < 64; ++d) s += Wk[c * 128 + n * 64 + d] * q[n * 64 + d];
  qk[c * 2 + n] = s;
}

// One pass over x per step: per (b, 64-pixel chunk) compute raw scores,
// chunk-local softmax stats (m, Z) and partial attn-weighted sums xa.
// Score phase: thread-per-(pixel, quarter), stride-4 channel interleave
// (conflict-free LDS), quad shfl reduce — no serial per-pixel rounds.
// part layout per (b,ch): [0]=m0 [1]=m1 [2]=Z0 [3]=Z1 [4..259]=xa0 [260..515]=xa1 (stride 520)
__global__ void poolpart_kernel(const float* __restrict__ x, const float* __restrict__ qk,
                                float* __restrict__ scores, float* __restrict__ part) {
  __shared__ float xs[64][260];
  __shared__ float ds[2][64];
  __shared__ float qks[512];
  int ch = blockIdx.x, b = blockIdx.y, tid = threadIdx.x;
  int s0 = ch * 64;
  const float* xb = x + ((size_t)b * 1024 + s0) * 256;
  for (int i = tid; i < 4096; i += 256) {
    int r = i >> 6, c4 = (i & 63) << 2;
    *(float4*)(&xs[r][c4]) = *(const float4*)(xb + (size_t)r * 256 + c4);
  }
  for (int i = tid; i < 512; i += 256) qks[i] = qk[i];
  __syncthreads();

  // ---- scores: thread (p, qd) sums channels c = 4j + qd ----
  int p = tid >> 2, qd = tid & 3;
  float d0 = 0.f, d1 = 0.f;
  const float* xr = &xs[p][qd];
  const float* qr = qks + 2 * qd;
#pragma unroll 8
  for (int j = 0; j < 64; ++j) {
    float xv = xr[4 * j];
    d0 += xv * qr[8 * j];
    d1 += xv * qr[8 * j + 1];
  }
  d0 += __shfl_xor(d0, 1, 64); d0 += __shfl_xor(d0, 2, 64);
  d1 += __shfl_xor(d1, 1, 64); d1 += __shfl_xor(d1, 2, 64);
  if (qd == 0) {
    ds[0][p] = d0 * 0.125f;
    ds[1][p] = d1 * 0.125f;
    scores[((size_t)b * 2 + 0) * 1024 + s0 + p] = d0 * 0.125f;
    scores[((size_t)b * 2 + 1) * 1024 + s0 + p] = d1 * 0.125f;
  }
  __syncthreads();

  int lane = tid & 63, wv = tid >> 6;
  if (wv < 2) {
    float v = ds[wv][lane];
    float m = v;
#pragma unroll
    for (int sh = 32; sh >= 1; sh >>= 1) m = fmaxf(m, __shfl_xor(m, sh, 64));
    float e = expf(v - m);
    float Z = e;
#pragma unroll
    for (int sh = 32; sh >= 1; sh >>= 1) Z += __shfl_xor(Z, sh, 64);
    ds[wv][lane] = e;
    if (lane == 0) {
      float* o = part + ((size_t)(b * 16 + ch)) * 520;
      o[wv] = m;
      o[2 + wv] = Z;
    }
  }
  __syncthreads();
  float a0 = 0.f, a1 = 0.f;
  for (int s = 0; s < 64; ++s) {
    float xv = xs[s][tid];
    a0 += ds[0][s] * xv;
    a1 += ds[1][s] * xv;
  }
  float* o = part + ((size_t)(b * 16 + ch)) * 520;
  o[4 + tid] = a0;
  o[4 + 256 + tid] = a1;
}

// reconcile partials -> rowscale + pooled -> logits -> top-2 routing (fused)
__global__ void route_kernel(const float* __restrict__ part, const float* __restrict__ scores,
                             const float* __restrict__ Wv, const float* __restrict__ Wmlp,
                             const float* __restrict__ alpha, float* __restrict__ allowed,
                             float* __restrict__ rowscale,
                             int* __restrict__ selE, float* __restrict__ selW, int step) {
  __shared__ float xs[512];
  __shared__ float pooled[128];
  __shared__ float lg[4];
  __shared__ float Msh[2], iZsh[2];
  int b = blockIdx.x, tid = threadIdx.x;
  if (tid < 2) {
    float m = -1e30f;
    for (int ch = 0; ch < 16; ++ch)
      m = fmaxf(m, part[((size_t)(b * 16 + ch)) * 520 + tid]);
    float z = 0.f;
    for (int ch = 0; ch < 16; ++ch) {
      const float* p = part + ((size_t)(b * 16 + ch)) * 520;
      z += expf(p[tid] - m) * p[2 + tid];
    }
    Msh[tid] = m;
    iZsh[tid] = 1.f / z;
  }
  __syncthreads();
  float M0 = Msh[0], M1 = Msh[1], iZ0 = iZsh[0], iZ1 = iZsh[1];
  {
    float al = alpha[0];
    float a = (al > 20.f) ? al : log1pf(expf(al));
    float k = 0.5f * 1024.f * a;
    for (int i = tid; i < 1024; i += 256) {
      float d0 = scores[((size_t)b * 2 + 0) * 1024 + i];
      float d1 = scores[((size_t)b * 2 + 1) * 1024 + i];
      rowscale[(size_t)b * 1024 + i] = 1.f + k * (expf(d0 - M0) * iZ0 + expf(d1 - M1) * iZ1);
    }
  }
#pragma unroll
  for (int i = 0; i < 2; ++i) {
    int id = tid + i * 256;
    int n = id >> 8, c = id & 255;
    float s = 0.f;
    for (int ch = 0; ch < 16; ++ch) {
      const float* p = part + ((size_t)(b * 16 + ch)) * 520;
      s += expf(p[n] - Msh[n]) * p[4 + n * 256 + c];
    }
    xs[id] = s * iZsh[n];
  }
  __syncthreads();
  if (tid < 128) {
    int n = tid >> 6;
    float s = 0.f;
    const float* xr = xs + n * 256;
    for (int c = 0; c < 256; ++c) s += xr[c] * Wv[(size_t)c * 128 + tid];
    pooled[tid] = s;
  }
  __syncthreads();
  if (tid < 4) {
    float s = 0.f;
    for (int d = 0; d < 128; ++d) s += pooled[d] * Wmlp[d * 4 + tid];
    lg[tid] = s;
  }
  __syncthreads();
  if (tid == 0) {
    float al[KK];
    if (step == 0) { for (int k = 0; k < KK; ++k) al[k] = 1.f; }
    else           { for (int k = 0; k < KK; ++k) al[k] = allowed[b * KK + k]; }
    float ml[KK];
    for (int k = 0; k < KK; ++k)
      ml[k] = (al[k] > 0.5f) ? lg[k] * (1.f / 1.5f) : (-1e9f) * (1.f / 1.5f);
    float m = ml[0];
    for (int k = 1; k < KK; ++k) m = fmaxf(m, ml[k]);
    float e[KK], ssum = 0.f;
    for (int k = 0; k < KK; ++k) { e[k] = expf(ml[k] - m); ssum += e[k]; }
    float w[KK];
    for (int k = 0; k < KK; ++k) w[k] = e[k] / ssum;
    int i0 = 0;
    for (int k = 1; k < KK; ++k) if (w[k] > w[i0]) i0 = k;
    int i1 = -1;
    for (int k = 0; k < KK; ++k) {
      if (k == i0) continue;
      if (i1 < 0 || w[k] > w[i1]) i1 = k;
    }
    float denom = w[i0] + w[i1] + 1e-9f;
    selE[b * 2 + 0] = i0;
    selE[b * 2 + 1] = i1;
    selW[b * 2 + 0] = w[i0] / denom;
    selW[b * 2 + 1] = w[i1] / denom;
    if (i0 != KK - 1) al[i0] = fminf(fmaxf(al[i0] - 1.f, 0.f), 1.f);
    al[KK - 1] = fmaxf(al[KK - 1], 1.f);
    for (int k = 0; k < KK; ++k) allowed[b * KK + k] = al[k];
  }
}

// Per-batch combined expert weights (exact f32 combine) -> f16 (pkrtz),
// transposed: Wc_h[(b*72 + tile)*8192 + co*32 + ki]
__global__ void combine_w_kernel(const float* __restrict__ We,
                                 const int* __restrict__ selE, const float* __restrict__ selW,
                                 unsigned short* __restrict__ Wc_h) {
  int tile = blockIdx.x;  // 0..71 = tap*8+kc
  int b = blockIdx.y;
  int tap = tile >> 3, kc = tile & 7;
  int co = threadIdx.x;
  int e0 = selE[b * 2], e1 = selE[b * 2 + 1];
  float w0 = selW[b * 2], w1 = selW[b * 2 + 1];
  __shared__ float ts[32][257];
  const float* s0 = We + (size_t)(e0 * 9 + tap) * 65536 + (size_t)(kc * 32) * 256 + co;
  const float* s1 = We + (size_t)(e1 * 9 + tap) * 65536 + (size_t)(kc * 32) * 256 + co;
  for (int ci = 0; ci < 32; ++ci)
    ts[ci][co] = w0 * s0[(size_t)ci * 256] + w1 * s1[(size_t)ci * 256];
  __syncthreads();
  unsigned int hw[16];
#pragma unroll
  for (int k2 = 0; k2 < 16; ++k2) hw[k2] = pk2h(ts[k2 * 2][co], ts[k2 * 2 + 1][co]);
  size_t base = ((size_t)b * 72 + tile) * 8192 + (size_t)co * 32;
#pragma unroll
  for (int j = 0; j < 4; ++j)
    *(uint4*)(Wc_h + base + j * 8) = make_uint4(hw[j * 4], hw[j * 4 + 1], hw[j * 4 + 2], hw[j * 4 + 3]);
}

// MFMA implicit-GEMM conv, single-f16 (proven config). Block = 256 thr
// (4 waves, 2m x 2n), M=128 pixels, N=128 cos; wave tile 64x64. x (f16)
// double-buffered in XOR-swizzled LDS; w via global_load_lds into 3-tile
// GROUP buffers (double-buffered). One vmcnt(0)+s_barrier per 3-tap group;
// stage_x for kc+1 overlapped under kc's first group. rowscale cached in
// LDS; f16 conversion via v_cvt_pkrtz.
__global__ __launch_bounds__(256, 2) void conv_kernel(
    const float* __restrict__ xin, const float* __restrict__ rowscale,
    const unsigned short* __restrict__ Wc_h,
    const float* __restrict__ be,
    const int* __restrict__ selE, const float* __restrict__ selW,
    float* __restrict__ out) {
  __shared__ __align__(16) unsigned char xsB[2][NCELL * 64];  // 2 x 13056
  __shared__ __align__(16) unsigned char BsB[2][3 * 8192];    // 2 x 24576
  __shared__ float rs_lds[NCELL];                             // 816 B

  int bid = blockIdx.x;
  int xcd = bid & 7, t2b = bid >> 3;
  int mt = t2b & 7, gs = t2b >> 3;
  int g = gs * 8 + xcd;           // (b,nt) group; its 8 mt-blocks share one XCD
  int b = g >> 1, nt = g & 1;
  int h0 = mt * 4;
  int tid = threadIdx.x;
  int lane = tid & 63, wid = tid >> 6;
  int wm = wid >> 1, wn = wid & 1;
  int l15 = lane & 15, kl = lane >> 4;

  int e0 = selE[b * 2], e1 = selE[b * 2 + 1];
  float w0 = selW[b * 2], w1 = selW[b * 2 + 1];

  int cellb[4];
#pragma unroll
  for (int mf = 0; mf < 4; ++mf) {
    int p0 = wm * 64 + mf * 16;
    cellb[mf] = (p0 >> 5) * XC + (p0 & 31) + l15;
  }
  int bbyte[4];
#pragma unroll
  for (int nf = 0; nf < 4; ++nf) {
    int co = wn * 64 + nf * 16 + l15;
    bbyte[nf] = (co * 64 + kl * 16) ^ ((co & 7) << 4);
  }
  // gll source pre-swizzle: dest oh -> (co, s) with LDS[(co*64+s*16)^((co&7)<<4)] = W[co][s*8..]
  int elemoff[2];
#pragma unroll
  for (int j = 0; j < 2; ++j) {
    int oh = wid * 2048 + j * 1024 + lane * 16;
    int co = ((oh >> 7) << 1) | (((oh >> 6) ^ (oh >> 8)) & 1);
    int s = ((oh >> 4) & 3) ^ (co & 3);
    elemoff[j] = (nt * 128 + co) * 32 + s * 8;
  }
  const unsigned short* WH = Wc_h + (size_t)b * 72 * 8192;

  float bias[4];
#pragma unroll
  for (int nf = 0; nf < 4; ++nf) {
    int con = nt * 128 + wn * 64 + nf * 16 + l15;
    bias[nf] = w0 * be[e0 * 256 + con] + w1 * be[e1 * 256 + con];
  }

  f32x4 acc[4][4];
#pragma unroll
  for (int mf = 0; mf < 4; ++mf)
#pragma unroll
    for (int nf = 0; nf < 4; ++nf) acc[mf][nf] = (f32x4){0.f, 0.f, 0.f, 0.f};

  // fill rowscale cache (kc-invariant)
  for (int i = tid; i < NCELL; i += 256) {
    int r = i / XC, c = i - r * XC;
    int gr = h0 - 1 + r, gc = c - 1;
    float v = 0.f;
    if (gr >= 0 && gr < 32 && gc >= 0 && gc < 32)
      v = rowscale[(size_t)b * 1024 + gr * 32 + gc];
    rs_lds[i] = v;
  }

  // stage x (f16 pkrtz, x_mod fused) for K-chunk kcc into xsB[kcc&1]
  auto stage_x = [&](int kcc) {
    unsigned char* xd = xsB[kcc & 1];
    for (int idx = tid; idx < NCELL * 2; idx += 256) {
      int hk = (idx >= NCELL) ? 1 : 0;
      int cell = idx - hk * NCELL;
      int r = cell / XC, c = cell - r * XC;
      int gr = h0 - 1 + r, gc = c - 1;
      uint4 pk = make_uint4(0, 0, 0, 0), pk2 = make_uint4(0, 0, 0, 0);
      if (gr >= 0 && gr < 32 && gc >= 0 && gc < 32) {
        const float* src = xin + (((size_t)b * 32 + gr) * 32 + gc) * 256 + kcc * 32 + hk * 16;
        float sc = rs_lds[cell];
        float xv[16];
        *(float4*)(xv + 0) = *(const float4*)(src + 0);
        *(float4*)(xv + 4) = *(const float4*)(src + 4);
        *(float4*)(xv + 8) = *(const float4*)(src + 8);
        *(float4*)(xv + 12) = *(const float4*)(src + 12);
        unsigned int u[8];
#pragma unroll
        for (int e2 = 0; e2 < 8; ++e2)
          u[e2] = pk2h(xv[e2 * 2] * sc, xv[e2 * 2 + 1] * sc);
        pk = make_uint4(u[0], u[1], u[2], u[3]);
        pk2 = make_uint4(u[4], u[5], u[6], u[7]);
      }
      int sx = (cell & 7) << 4;
      int b0 = (cell * 64 + hk * 32) ^ sx;
      int b1 = (cell * 64 + hk * 32 + 16) ^ sx;
      *(uint4*)(xd + b0) = pk;
      *(uint4*)(xd + b1) = pk2;
    }
  };

  auto issue_group = [&](int kcA, int subBase, int buf) {
#pragma unroll
    for (int t = 0; t < 3; ++t) {
      const unsigned short* sp = WH + (size_t)((subBase + t) * 8 + kcA) * 8192;
      char* lb = (char*)&BsB[buf][t * 8192] + wid * 2048;
      gll16(sp + elemoff[0], lb);
      gll16(sp + elemoff[1], lb + 1024);
    }
    SCHED0;
  };

  auto do_tap = [&](int tap, int tIdx, const unsigned char* xsCur, int buf) {
    const int dy = (tap >= 6) ? 2 : ((tap >= 3) ? 1 : 0);
    const int dx = tap - dy * 3;
    const int dcell = dy * XC + dx;
    const unsigned char* bp = &BsB[buf][tIdx * 8192];
    f16x8 af[4], bf[4];
#pragma unroll
    for (int mf = 0; mf < 4; ++mf) {
      int cell = cellb[mf] + dcell;
      int abyte = (cell * 64 + kl * 16) ^ ((cell & 7) << 4);
      af[mf] = *(const f16x8*)(xsCur + abyte);
    }
#pragma unroll
    for (int nf = 0; nf < 4; ++nf) bf[nf] = *(const f16x8*)(bp + bbyte[nf]);
    __builtin_amdgcn_s_setprio(1);
#pragma unroll
    for (int mf = 0; mf < 4; ++mf)
#pragma unroll
      for (int nf = 0; nf < 4; ++nf)
        acc[mf][nf] = __builtin_amdgcn_mfma_f32_16x16x32_f16(af[mf], bf[nf], acc[mf][nf], 0, 0, 0);
    __builtin_amdgcn_s_setprio(0);
  };

  // ---- prologue ----
  issue_group(0, 0, 0);
  __syncthreads();   // rs_lds visible to all before stage_x uses it
  stage_x(0);
  S_VMCNT0;
  S_LGKM0;
  SCHED0;
  __builtin_amdgcn_s_barrier();

#pragma unroll 1
  for (int kc = 0; kc < 8; ++kc) {
    const unsigned char* xsCur = xsB[kc & 1];
    const int bX = kc & 1;
    // group 0: taps 0-2 from BsB[bX]; overlap next-kc x staging
    if (kc < 7) stage_x(kc + 1);
    issue_group(kc, 3, bX ^ 1);
    do_tap(0, 0, xsCur, bX);
    do_tap(1, 1, xsCur, bX);
    do_tap(2, 2, xsCur, bX);
    S_VMCNT0;
    SCHED0;
    __builtin_amdgcn_s_barrier();
    // group 1: taps 3-5 from BsB[bX^1]
    issue_group(kc, 6, bX);
    do_tap(3, 0, xsCur, bX ^ 1);
    do_tap(4, 1, xsCur, bX ^ 1);
    do_tap(5, 2, xsCur, bX ^ 1);
    S_VMCNT0;
    SCHED0;
    __builtin_amdgcn_s_barrier();
    // group 2: taps 6-8 from BsB[bX]
    if (kc < 7) issue_group(kc + 1, 0, bX ^ 1);
    do_tap(6, 0, xsCur, bX);
    do_tap(7, 1, xsCur, bX);
    do_tap(8, 2, xsCur, bX);
    if (kc < 7) { S_LGKM0; }  // xs writes for kc+1 (issued in group 0) drained
    S_VMCNT0;
    SCHED0;
    __builtin_amdgcn_s_barrier();
  }

#pragma unroll
  for (int mf = 0; mf < 4; ++mf) {
    int p0 = wm * 64 + mf * 16;
    int pr = p0 >> 5, pc = p0 & 31;
    size_t rowbase = ((size_t)b * 32 + h0 + pr) * 32;
#pragma unroll
    for (int nf = 0; nf < 4; ++nf) {
      int co = nt * 128 + wn * 64 + nf * 16 + l15;
#pragma unroll
      for (int rr = 0; rr < 4; ++rr) {
        int col = pc + kl * 4 + rr;
        out[(rowbase + col) * 256 + co] = acc[mf][nf][rr] + bias[nf];
      }
    }
  }
}

extern "C" void kernel_launch(void* const* d_in, const int* in_sizes, int n_in,
                              void* d_out, int out_size, void* d_ws, size_t ws_size,
                              hipStream_t stream) {
  const float* x_in  = (const float*)d_in[0];
  const float* q     = (const float*)d_in[1];
  const float* Wk    = (const float*)d_in[2];
  const float* Wv    = (const float*)d_in[3];
  const float* Wmlp  = (const float*)d_in[4];
  const float* alpha = (const float*)d_in[5];
  const float* We    = (const float*)d_in[6];
  const float* be    = (const float*)d_in[7];
  float* out = (float*)d_out;
  float* ws = (float*)d_ws;

  float* qk       = ws;                  // 512
  float* scores   = qk + 512;            // 65536
  float* rowscale = scores + 65536;      // 32768
  float* part     = rowscale + 32768;    // 32*16*520 = 266240
  float* allowed  = part + 266240;       // 128
  float* selW     = allowed + 128;       // 64
  int*   selE     = (int*)(selW + 64);   // 64
  float* xbuf     = selW + 128;          // 8388608 floats
  unsigned short* Wc_h = (unsigned short*)(xbuf + 8388608);  // 18,874,368 ushorts

  qk_kernel<<<2, 256, 0, stream>>>(Wk, q, qk);

  const float* step_in[3] = {x_in, out, xbuf};
  float* step_out[3] = {out, xbuf, out};

  for (int t = 0; t < 3; ++t) {
    const float* xc = step_in[t];
    poolpart_kernel<<<dim3(16, 32), 256, 0, stream>>>(xc, qk, scores, part);
    route_kernel<<<32, 256, 0, stream>>>(part, scores, Wv, Wmlp, alpha, allowed, rowscale, selE, selW, t);
    combine_w_kernel<<<dim3(72, 32), 256, 0, stream>>>(We, selE, selW, Wc_h);
    conv_kernel<<<512, 256, 0, stream>>>(xc, rowscale, Wc_h, be, selE, selW, step_out[t]);
  }
}

// Round 18
// 290.880 us; speedup vs baseline: 1.1682x; 1.0122x over previous
//
#include <hip/hip_runtime.h>

typedef _Float16 f16x8 __attribute__((ext_vector_type(8)));
typedef __fp16 fp16x2 __attribute__((ext_vector_type(2)));
typedef __attribute__((ext_vector_type(4))) float f32x4;

#define CC 256
#define SS 1024
#define KK 4
#define XR 6
#define XC 34
#define NCELL (XR * XC)  // 204

__device__ __forceinline__ unsigned int pk2h(float a, float b) {
  fp16x2 h = __builtin_amdgcn_cvt_pkrtz(a, b);
  return __builtin_bit_cast(unsigned int, h);
}

__device__ __forceinline__ void gll16(const void* g, void* l) {
  __builtin_amdgcn_global_load_lds((const __attribute__((address_space(1))) void*)g,
                                   (__attribute__((address_space(3))) void*)l, 16, 0, 0);
}

#define S_VMCNT0 asm volatile("s_waitcnt vmcnt(0)" ::: "memory")
#define S_LGKM0 asm volatile("s_waitcnt lgkmcnt(0)" ::: "memory")
#define SCHED0 __builtin_amdgcn_sched_barrier(0)

// qk[c][n] = sum_d Wk[c, n*64+d] * q[n, d]
__global__ void qk_kernel(const float* __restrict__ Wk, const float* __restrict__ q,
                          float* __restrict__ qk) {
  int t = blockIdx.x * blockDim.x + threadIdx.x;
  if (t >= CC * 2) return;
  int c = t >> 1, n = t & 1;
  float s = 0.f;
  for (int d = 0; d < 64; ++d) s += Wk[c * 128 + n * 64 + d] * q[n * 64 + d];
  qk[c * 2 + n] = s;
}

// One pass over x per step: per (b, 64-pixel chunk) compute raw scores,
// chunk-local softmax stats (m, Z) and partial attn-weighted sums xa.
// part layout per (b,ch): [0]=m0 [1]=m1 [2]=Z0 [3]=Z1 [4..259]=xa0 [260..515]=xa1 (stride 520)
__global__ void poolpart_kernel(const float* __restrict__ x, const float* __restrict__ qk,
                                float* __restrict__ scores, float* __restrict__ part) {
  __shared__ float xs[64][260];
  __shared__ float ds[2][64];
  __shared__ float qks[512];
  int ch = blockIdx.x, b = blockIdx.y, tid = threadIdx.x;
  int s0 = ch * 64;
  const float* xb = x + ((size_t)b * 1024 + s0) * 256;
  for (int i = tid; i < 4096; i += 256) {
    int r = i >> 6, c4 = (i & 63) << 2;
    *(float4*)(&xs[r][c4]) = *(const float4*)(xb + (size_t)r * 256 + c4);
  }
  for (int i = tid; i < 512; i += 256) qks[i] = qk[i];
  __syncthreads();

  // ---- scores: thread (p, qd) sums channels c = 4j + qd ----
  int p = tid >> 2, qd = tid & 3;
  float d0 = 0.f, d1 = 0.f;
  const float* xr = &xs[p][qd];
  const float* qr = qks + 2 * qd;
#pragma unroll 8
  for (int j = 0; j < 64; ++j) {
    float xv = xr[4 * j];
    d0 += xv * qr[8 * j];
    d1 += xv * qr[8 * j + 1];
  }
  d0 += __shfl_xor(d0, 1, 64); d0 += __shfl_xor(d0, 2, 64);
  d1 += __shfl_xor(d1, 1, 64); d1 += __shfl_xor(d1, 2, 64);
  if (qd == 0) {
    ds[0][p] = d0 * 0.125f;
    ds[1][p] = d1 * 0.125f;
    scores[((size_t)b * 2 + 0) * 1024 + s0 + p] = d0 * 0.125f;
    scores[((size_t)b * 2 + 1) * 1024 + s0 + p] = d1 * 0.125f;
  }
  __syncthreads();

  int lane = tid & 63, wv = tid >> 6;
  if (wv < 2) {
    float v = ds[wv][lane];
    float m = v;
#pragma unroll
    for (int sh = 32; sh >= 1; sh >>= 1) m = fmaxf(m, __shfl_xor(m, sh, 64));
    float e = expf(v - m);
    float Z = e;
#pragma unroll
    for (int sh = 32; sh >= 1; sh >>= 1) Z += __shfl_xor(Z, sh, 64);
    ds[wv][lane] = e;
    if (lane == 0) {
      float* o = part + ((size_t)(b * 16 + ch)) * 520;
      o[wv] = m;
      o[2 + wv] = Z;
    }
  }
  __syncthreads();
  // xa accumulate with 4 independent chains per head (ILP)
  float a0a = 0.f, a0b = 0.f, a0c = 0.f, a0d = 0.f;
  float a1a = 0.f, a1b = 0.f, a1c = 0.f, a1d = 0.f;
#pragma unroll 4
  for (int s4 = 0; s4 < 16; ++s4) {
    float x0 = xs[s4 * 4 + 0][tid];
    float x1 = xs[s4 * 4 + 1][tid];
    float x2 = xs[s4 * 4 + 2][tid];
    float x3 = xs[s4 * 4 + 3][tid];
    a0a += ds[0][s4 * 4 + 0] * x0;
    a0b += ds[0][s4 * 4 + 1] * x1;
    a0c += ds[0][s4 * 4 + 2] * x2;
    a0d += ds[0][s4 * 4 + 3] * x3;
    a1a += ds[1][s4 * 4 + 0] * x0;
    a1b += ds[1][s4 * 4 + 1] * x1;
    a1c += ds[1][s4 * 4 + 2] * x2;
    a1d += ds[1][s4 * 4 + 3] * x3;
  }
  float* o = part + ((size_t)(b * 16 + ch)) * 520;
  o[4 + tid] = (a0a + a0b) + (a0c + a0d);
  o[4 + 256 + tid] = (a1a + a1b) + (a1c + a1d);
}

// reconcile partials -> rowscale + pooled -> logits -> top-2 routing (fused)
__global__ void route_kernel(const float* __restrict__ part, const float* __restrict__ scores,
                             const float* __restrict__ Wv, const float* __restrict__ Wmlp,
                             const float* __restrict__ alpha, float* __restrict__ allowed,
                             float* __restrict__ rowscale,
                             int* __restrict__ selE, float* __restrict__ selW, int step) {
  __shared__ float xs[512];
  __shared__ float phalf[256];
  __shared__ float pooled[128];
  __shared__ float lg[4];
  __shared__ float Msh[2], iZsh[2];
  __shared__ float cs[2][16];
  int b = blockIdx.x, tid = threadIdx.x;
  if (tid < 2) {
    float m = -1e30f;
    for (int ch = 0; ch < 16; ++ch)
      m = fmaxf(m, part[((size_t)(b * 16 + ch)) * 520 + tid]);
    float z = 0.f;
    for (int ch = 0; ch < 16; ++ch) {
      const float* p = part + ((size_t)(b * 16 + ch)) * 520;
      z += expf(p[tid] - m) * p[2 + tid];
    }
    Msh[tid] = m;
    iZsh[tid] = 1.f / z;
  }
  __syncthreads();
  if (tid < 32) {
    int n = tid >> 4, ch = tid & 15;
    cs[n][ch] = expf(part[((size_t)(b * 16 + ch)) * 520 + n] - Msh[n]);
  }
  float M0 = Msh[0], M1 = Msh[1], iZ0 = iZsh[0], iZ1 = iZsh[1];
  {
    float al = alpha[0];
    float a = (al > 20.f) ? al : log1pf(expf(al));
    float k = 0.5f * 1024.f * a;
    for (int i = tid; i < 1024; i += 256) {
      float d0 = scores[((size_t)b * 2 + 0) * 1024 + i];
      float d1 = scores[((size_t)b * 2 + 1) * 1024 + i];
      rowscale[(size_t)b * 1024 + i] = 1.f + k * (expf(d0 - M0) * iZ0 + expf(d1 - M1) * iZ1);
    }
  }
  __syncthreads();
#pragma unroll
  for (int i = 0; i < 2; ++i) {
    int id = tid + i * 256;
    int n = id >> 8, c = id & 255;
    float s = 0.f;
    for (int ch = 0; ch < 16; ++ch)
      s += cs[n][ch] * part[((size_t)(b * 16 + ch)) * 520 + 4 + n * 256 + c];
    xs[id] = s * iZsh[n];
  }
  __syncthreads();
  // pooled GEMV split-K over 256 threads: thread = (half, d)
  {
    int d = tid & 127, half = tid >> 7;
    int n = d >> 6;
    const float* xr = xs + n * 256 + half * 128;
    const float* wv = Wv + (size_t)half * 128 * 128 + d;
    float s = 0.f;
#pragma unroll 4
    for (int c = 0; c < 128; ++c) s += xr[c] * wv[(size_t)c * 128];
    phalf[tid] = s;
  }
  __syncthreads();
  if (tid < 128) pooled[tid] = phalf[tid] + phalf[tid + 128];
  __syncthreads();
  if (tid < 4) {
    float s = 0.f;
    for (int d = 0; d < 128; ++d) s += pooled[d] * Wmlp[d * 4 + tid];
    lg[tid] = s;
  }
  __syncthreads();
  if (tid == 0) {
    float al[KK];
    if (step == 0) { for (int k = 0; k < KK; ++k) al[k] = 1.f; }
    else           { for (int k = 0; k < KK; ++k) al[k] = allowed[b * KK + k]; }
    float ml[KK];
    for (int k = 0; k < KK; ++k)
      ml[k] = (al[k] > 0.5f) ? lg[k] * (1.f / 1.5f) : (-1e9f) * (1.f / 1.5f);
    float m = ml[0];
    for (int k = 1; k < KK; ++k) m = fmaxf(m, ml[k]);
    float e[KK], ssum = 0.f;
    for (int k = 0; k < KK; ++k) { e[k] = expf(ml[k] - m); ssum += e[k]; }
    float w[KK];
    for (int k = 0; k < KK; ++k) w[k] = e[k] / ssum;
    int i0 = 0;
    for (int k = 1; k < KK; ++k) if (w[k] > w[i0]) i0 = k;
    int i1 = -1;
    for (int k = 0; k < KK; ++k) {
      if (k == i0) continue;
      if (i1 < 0 || w[k] > w[i1]) i1 = k;
    }
    float denom = w[i0] + w[i1] + 1e-9f;
    selE[b * 2 + 0] = i0;
    selE[b * 2 + 1] = i1;
    selW[b * 2 + 0] = w[i0] / denom;
    selW[b * 2 + 1] = w[i1] / denom;
    if (i0 != KK - 1) al[i0] = fminf(fmaxf(al[i0] - 1.f, 0.f), 1.f);
    al[KK - 1] = fmaxf(al[KK - 1], 1.f);
    for (int k = 0; k < KK; ++k) allowed[b * KK + k] = al[k];
  }
}

// Per-batch combined expert weights (exact f32 combine) -> f16 (pkrtz),
// transposed: Wc_h[(b*72 + tile)*8192 + co*32 + ki]
__global__ void combine_w_kernel(const float* __restrict__ We,
                                 const int* __restrict__ selE, const float* __restrict__ selW,
                                 unsigned short* __restrict__ Wc_h) {
  int tile = blockIdx.x;  // 0..71 = tap*8+kc
  int b = blockIdx.y;
  int tap = tile >> 3, kc = tile & 7;
  int co = threadIdx.x;
  int e0 = selE[b * 2], e1 = selE[b * 2 + 1];
  float w0 = selW[b * 2], w1 = selW[b * 2 + 1];
  __shared__ float ts[32][257];
  const float* s0 = We + (size_t)(e0 * 9 + tap) * 65536 + (size_t)(kc * 32) * 256 + co;
  const float* s1 = We + (size_t)(e1 * 9 + tap) * 65536 + (size_t)(kc * 32) * 256 + co;
  for (int ci = 0; ci < 32; ++ci)
    ts[ci][co] = w0 * s0[(size_t)ci * 256] + w1 * s1[(size_t)ci * 256];
  __syncthreads();
  unsigned int hw[16];
#pragma unroll
  for (int k2 = 0; k2 < 16; ++k2) hw[k2] = pk2h(ts[k2 * 2][co], ts[k2 * 2 + 1][co]);
  size_t base = ((size_t)b * 72 + tile) * 8192 + (size_t)co * 32;
#pragma unroll
  for (int j = 0; j < 4; ++j)
    *(uint4*)(Wc_h + base + j * 8) = make_uint4(hw[j * 4], hw[j * 4 + 1], hw[j * 4 + 2], hw[j * 4 + 3]);
}

// MFMA implicit-GEMM conv, single-f16 (proven config, unchanged from R17).
__global__ __launch_bounds__(256, 2) void conv_kernel(
    const float* __restrict__ xin, const float* __restrict__ rowscale,
    const unsigned short* __restrict__ Wc_h,
    const float* __restrict__ be,
    const int* __restrict__ selE, const float* __restrict__ selW,
    float* __restrict__ out) {
  __shared__ __align__(16) unsigned char xsB[2][NCELL * 64];  // 2 x 13056
  __shared__ __align__(16) unsigned char BsB[2][3 * 8192];    // 2 x 24576
  __shared__ float rs_lds[NCELL];                             // 816 B

  int bid = blockIdx.x;
  int xcd = bid & 7, t2b = bid >> 3;
  int mt = t2b & 7, gs = t2b >> 3;
  int g = gs * 8 + xcd;           // (b,nt) group; its 8 mt-blocks share one XCD
  int b = g >> 1, nt = g & 1;
  int h0 = mt * 4;
  int tid = threadIdx.x;
  int lane = tid & 63, wid = tid >> 6;
  int wm = wid >> 1, wn = wid & 1;
  int l15 = lane & 15, kl = lane >> 4;

  int e0 = selE[b * 2], e1 = selE[b * 2 + 1];
  float w0 = selW[b * 2], w1 = selW[b * 2 + 1];

  int cellb[4];
#pragma unroll
  for (int mf = 0; mf < 4; ++mf) {
    int p0 = wm * 64 + mf * 16;
    cellb[mf] = (p0 >> 5) * XC + (p0 & 31) + l15;
  }
  int bbyte[4];
#pragma unroll
  for (int nf = 0; nf < 4; ++nf) {
    int co = wn * 64 + nf * 16 + l15;
    bbyte[nf] = (co * 64 + kl * 16) ^ ((co & 7) << 4);
  }
  int elemoff[2];
#pragma unroll
  for (int j = 0; j < 2; ++j) {
    int oh = wid * 2048 + j * 1024 + lane * 16;
    int co = ((oh >> 7) << 1) | (((oh >> 6) ^ (oh >> 8)) & 1);
    int s = ((oh >> 4) & 3) ^ (co & 3);
    elemoff[j] = (nt * 128 + co) * 32 + s * 8;
  }
  const unsigned short* WH = Wc_h + (size_t)b * 72 * 8192;

  float bias[4];
#pragma unroll
  for (int nf = 0; nf < 4; ++nf) {
    int con = nt * 128 + wn * 64 + nf * 16 + l15;
    bias[nf] = w0 * be[e0 * 256 + con] + w1 * be[e1 * 256 + con];
  }

  f32x4 acc[4][4];
#pragma unroll
  for (int mf = 0; mf < 4; ++mf)
#pragma unroll
    for (int nf = 0; nf < 4; ++nf) acc[mf][nf] = (f32x4){0.f, 0.f, 0.f, 0.f};

  for (int i = tid; i < NCELL; i += 256) {
    int r = i / XC, c = i - r * XC;
    int gr = h0 - 1 + r, gc = c - 1;
    float v = 0.f;
    if (gr >= 0 && gr < 32 && gc >= 0 && gc < 32)
      v = rowscale[(size_t)b * 1024 + gr * 32 + gc];
    rs_lds[i] = v;
  }

  auto stage_x = [&](int kcc) {
    unsigned char* xd = xsB[kcc & 1];
    for (int idx = tid; idx < NCELL * 2; idx += 256) {
      int hk = (idx >= NCELL) ? 1 : 0;
      int cell = idx - hk * NCELL;
      int r = cell / XC, c = cell - r * XC;
      int gr = h0 - 1 + r, gc = c - 1;
      uint4 pk = make_uint4(0, 0, 0, 0), pk2 = make_uint4(0, 0, 0, 0);
      if (gr >= 0 && gr < 32 && gc >= 0 && gc < 32) {
        const float* src = xin + (((size_t)b * 32 + gr) * 32 + gc) * 256 + kcc * 32 + hk * 16;
        float sc = rs_lds[cell];
        float xv[16];
        *(float4*)(xv + 0) = *(const float4*)(src + 0);
        *(float4*)(xv + 4) = *(const float4*)(src + 4);
        *(float4*)(xv + 8) = *(const float4*)(src + 8);
        *(float4*)(xv + 12) = *(const float4*)(src + 12);
        unsigned int u[8];
#pragma unroll
        for (int e2 = 0; e2 < 8; ++e2)
          u[e2] = pk2h(xv[e2 * 2] * sc, xv[e2 * 2 + 1] * sc);
        pk = make_uint4(u[0], u[1], u[2], u[3]);
        pk2 = make_uint4(u[4], u[5], u[6], u[7]);
      }
      int sx = (cell & 7) << 4;
      int b0 = (cell * 64 + hk * 32) ^ sx;
      int b1 = (cell * 64 + hk * 32 + 16) ^ sx;
      *(uint4*)(xd + b0) = pk;
      *(uint4*)(xd + b1) = pk2;
    }
  };

  auto issue_group = [&](int kcA, int subBase, int buf) {
#pragma unroll
    for (int t = 0; t < 3; ++t) {
      const unsigned short* sp = WH + (size_t)((subBase + t) * 8 + kcA) * 8192;
      char* lb = (char*)&BsB[buf][t * 8192] + wid * 2048;
      gll16(sp + elemoff[0], lb);
      gll16(sp + elemoff[1], lb + 1024);
    }
    SCHED0;
  };

  auto do_tap = [&](int tap, int tIdx, const unsigned char* xsCur, int buf) {
    const int dy = (tap >= 6) ? 2 : ((tap >= 3) ? 1 : 0);
    const int dx = tap - dy * 3;
    const int dcell = dy * XC + dx;
    const unsigned char* bp = &BsB[buf][tIdx * 8192];
    f16x8 af[4], bf[4];
#pragma unroll
    for (int mf = 0; mf < 4; ++mf) {
      int cell = cellb[mf] + dcell;
      int abyte = (cell * 64 + kl * 16) ^ ((cell & 7) << 4);
      af[mf] = *(const f16x8*)(xsCur + abyte);
    }
#pragma unroll
    for (int nf = 0; nf < 4; ++nf) bf[nf] = *(const f16x8*)(bp + bbyte[nf]);
    __builtin_amdgcn_s_setprio(1);
#pragma unroll
    for (int mf = 0; mf < 4; ++mf)
#pragma unroll
      for (int nf = 0; nf < 4; ++nf)
        acc[mf][nf] = __builtin_amdgcn_mfma_f32_16x16x32_f16(af[mf], bf[nf], acc[mf][nf], 0, 0, 0);
    __builtin_amdgcn_s_setprio(0);
  };

  // ---- prologue ----
  issue_group(0, 0, 0);
  __syncthreads();   // rs_lds visible to all before stage_x uses it
  stage_x(0);
  S_VMCNT0;
  S_LGKM0;
  SCHED0;
  __builtin_amdgcn_s_barrier();

#pragma unroll 1
  for (int kc = 0; kc < 8; ++kc) {
    const unsigned char* xsCur = xsB[kc & 1];
    const int bX = kc & 1;
    if (kc < 7) stage_x(kc + 1);
    issue_group(kc, 3, bX ^ 1);
    do_tap(0, 0, xsCur, bX);
    do_tap(1, 1, xsCur, bX);
    do_tap(2, 2, xsCur, bX);
    S_VMCNT0;
    SCHED0;
    __builtin_amdgcn_s_barrier();
    issue_group(kc, 6, bX);
    do_tap(3, 0, xsCur, bX ^ 1);
    do_tap(4, 1, xsCur, bX ^ 1);
    do_tap(5, 2, xsCur, bX ^ 1);
    S_VMCNT0;
    SCHED0;
    __builtin_amdgcn_s_barrier();
    if (kc < 7) issue_group(kc + 1, 0, bX ^ 1);
    do_tap(6, 0, xsCur, bX);
    do_tap(7, 1, xsCur, bX);
    do_tap(8, 2, xsCur, bX);
    if (kc < 7) { S_LGKM0; }
    S_VMCNT0;
    SCHED0;
    __builtin_amdgcn_s_barrier();
  }

#pragma unroll
  for (int mf = 0; mf < 4; ++mf) {
    int p0 = wm * 64 + mf * 16;
    int pr = p0 >> 5, pc = p0 & 31;
    size_t rowbase = ((size_t)b * 32 + h0 + pr) * 32;
#pragma unroll
    for (int nf = 0; nf < 4; ++nf) {
      int co = nt * 128 + wn * 64 + nf * 16 + l15;
#pragma unroll
      for (int rr = 0; rr < 4; ++rr) {
        int col = pc + kl * 4 + rr;
        out[(rowbase + col) * 256 + co] = acc[mf][nf][rr] + bias[nf];
      }
    }
  }
}

extern "C" void kernel_launch(void* const* d_in, const int* in_sizes, int n_in,
                              void* d_out, int out_size, void* d_ws, size_t ws_size,
                              hipStream_t stream) {
  const float* x_in  = (const float*)d_in[0];
  const float* q     = (const float*)d_in[1];
  const float* Wk    = (const float*)d_in[2];
  const float* Wv    = (const float*)d_in[3];
  const float* Wmlp  = (const float*)d_in[4];
  const float* alpha = (const float*)d_in[5];
  const float* We    = (const float*)d_in[6];
  const float* be    = (const float*)d_in[7];
  float* out = (float*)d_out;
  float* ws = (float*)d_ws;

  float* qk       = ws;                  // 512
  float* scores   = qk + 512;            // 65536
  float* rowscale = scores + 65536;      // 32768
  float* part     = rowscale + 32768;    // 32*16*520 = 266240
  float* allowed  = part + 266240;       // 128
  float* selW     = allowed + 128;       // 64
  int*   selE     = (int*)(selW + 64);   // 64
  float* xbuf     = selW + 128;          // 8388608 floats
  unsigned short* Wc_h = (unsigned short*)(xbuf + 8388608);  // 18,874,368 ushorts

  qk_kernel<<<2, 256, 0, stream>>>(Wk, q, qk);

  const float* step_in[3] = {x_in, out, xbuf};
  float* step_out[3] = {out, xbuf, out};

  for (int t = 0; t < 3; ++t) {
    const float* xc = step_in[t];
    poolpart_kernel<<<dim3(16, 32), 256, 0, stream>>>(xc, qk, scores, part);
    route_kernel<<<32, 256, 0, stream>>>(part, scores, Wv, Wmlp, alpha, allowed, rowscale, selE, selW, t);
    combine_w_kernel<<<dim3(72, 32), 256, 0, stream>>>(We, selE, selW, Wc_h);
    conv_kernel<<<512, 256, 0, stream>>>(xc, rowscale, Wc_h, be, selE, selW, step_out[t]);
  }
}

// Round 19
// 260.714 us; speedup vs baseline: 1.3033x; 1.1157x over previous
//
#include <hip/hip_runtime.h>

typedef _Float16 f16x8 __attribute__((ext_vector_type(8)));
typedef __fp16 fp16x2 __attribute__((ext_vector_type(2)));
typedef __attribute__((ext_vector_type(4))) float f32x4;

#define CC 256
#define SS 1024
#define KK 4
#define XR 6
#define XC 34
#define NCELL (XR * XC)  // 204

__device__ __forceinline__ unsigned int pk2h(float a, float b) {
  fp16x2 h = __builtin_amdgcn_cvt_pkrtz(a, b);
  return __builtin_bit_cast(unsigned int, h);
}

#define S_VMCNT0 asm volatile("s_waitcnt vmcnt(0)" ::: "memory")
#define S_LGKM0 asm volatile("s_waitcnt lgkmcnt(0)" ::: "memory")
#define SCHED0 __builtin_amdgcn_sched_barrier(0)

// qk[c][n] = sum_d Wk[c, n*64+d] * q[n, d]
__global__ void qk_kernel(const float* __restrict__ Wk, const float* __restrict__ q,
                          float* __restrict__ qk) {
  int t = blockIdx.x * blockDim.x + threadIdx.x;
  if (t >= CC * 2) return;
  int c = t >> 1, n = t & 1;
  float s = 0.f;
  for (int d = 0; d < 64; ++d) s += Wk[c * 128 + n * 64 + d] * q[n * 64 + d];
  qk[c * 2 + n] = s;
}

// One-time: all 4 experts' weights -> f16, transposed tiles:
// Wt[(e*72 + tile)*8192 + co*32 + ki]
__global__ void prep_w_kernel(const float* __restrict__ We, unsigned short* __restrict__ Wt) {
  int tile = blockIdx.x;  // 0..71 = tap*8+kc
  int e = blockIdx.y;
  int tap = tile >> 3, kc = tile & 7;
  int co = threadIdx.x;
  __shared__ float ts[32][257];
  const float* src = We + (size_t)(e * 9 + tap) * 65536 + (size_t)(kc * 32) * 256 + co;
  for (int ci = 0; ci < 32; ++ci) ts[ci][co] = src[(size_t)ci * 256];
  __syncthreads();
  unsigned int hw[16];
#pragma unroll
  for (int k2 = 0; k2 < 16; ++k2) hw[k2] = pk2h(ts[k2 * 2][co], ts[k2 * 2 + 1][co]);
  size_t base = ((size_t)e * 72 + tile) * 8192 + (size_t)co * 32;
#pragma unroll
  for (int j = 0; j < 4; ++j)
    *(uint4*)(Wt + base + j * 8) = make_uint4(hw[j * 4], hw[j * 4 + 1], hw[j * 4 + 2], hw[j * 4 + 3]);
}

// One pass over x per step: per (b, 64-pixel chunk) compute raw scores,
// chunk-local softmax stats (m, Z) and partial attn-weighted sums xa.
// part layout per (b,ch): [0]=m0 [1]=m1 [2]=Z0 [3]=Z1 [4..259]=xa0 [260..515]=xa1 (stride 520)
__global__ void poolpart_kernel(const float* __restrict__ x, const float* __restrict__ qk,
                                float* __restrict__ scores, float* __restrict__ part) {
  __shared__ float xs[64][260];
  __shared__ float ds[2][64];
  __shared__ float qks[512];
  int ch = blockIdx.x, b = blockIdx.y, tid = threadIdx.x;
  int s0 = ch * 64;
  const float* xb = x + ((size_t)b * 1024 + s0) * 256;
  for (int i = tid; i < 4096; i += 256) {
    int r = i >> 6, c4 = (i & 63) << 2;
    *(float4*)(&xs[r][c4]) = *(const float4*)(xb + (size_t)r * 256 + c4);
  }
  for (int i = tid; i < 512; i += 256) qks[i] = qk[i];
  __syncthreads();

  int p = tid >> 2, qd = tid & 3;
  float d0 = 0.f, d1 = 0.f;
  const float* xr = &xs[p][qd];
  const float* qr = qks + 2 * qd;
#pragma unroll 8
  for (int j = 0; j < 64; ++j) {
    float xv = xr[4 * j];
    d0 += xv * qr[8 * j];
    d1 += xv * qr[8 * j + 1];
  }
  d0 += __shfl_xor(d0, 1, 64); d0 += __shfl_xor(d0, 2, 64);
  d1 += __shfl_xor(d1, 1, 64); d1 += __shfl_xor(d1, 2, 64);
  if (qd == 0) {
    ds[0][p] = d0 * 0.125f;
    ds[1][p] = d1 * 0.125f;
    scores[((size_t)b * 2 + 0) * 1024 + s0 + p] = d0 * 0.125f;
    scores[((size_t)b * 2 + 1) * 1024 + s0 + p] = d1 * 0.125f;
  }
  __syncthreads();

  int lane = tid & 63, wv = tid >> 6;
  if (wv < 2) {
    float v = ds[wv][lane];
    float m = v;
#pragma unroll
    for (int sh = 32; sh >= 1; sh >>= 1) m = fmaxf(m, __shfl_xor(m, sh, 64));
    float e = expf(v - m);
    float Z = e;
#pragma unroll
    for (int sh = 32; sh >= 1; sh >>= 1) Z += __shfl_xor(Z, sh, 64);
    ds[wv][lane] = e;
    if (lane == 0) {
      float* o = part + ((size_t)(b * 16 + ch)) * 520;
      o[wv] = m;
      o[2 + wv] = Z;
    }
  }
  __syncthreads();
  float a0a = 0.f, a0b = 0.f, a0c = 0.f, a0d = 0.f;
  float a1a = 0.f, a1b = 0.f, a1c = 0.f, a1d = 0.f;
#pragma unroll 4
  for (int s4 = 0; s4 < 16; ++s4) {
    float x0 = xs[s4 * 4 + 0][tid];
    float x1 = xs[s4 * 4 + 1][tid];
    float x2 = xs[s4 * 4 + 2][tid];
    float x3 = xs[s4 * 4 + 3][tid];
    a0a += ds[0][s4 * 4 + 0] * x0;
    a0b += ds[0][s4 * 4 + 1] * x1;
    a0c += ds[0][s4 * 4 + 2] * x2;
    a0d += ds[0][s4 * 4 + 3] * x3;
    a1a += ds[1][s4 * 4 + 0] * x0;
    a1b += ds[1][s4 * 4 + 1] * x1;
    a1c += ds[1][s4 * 4 + 2] * x2;
    a1d += ds[1][s4 * 4 + 3] * x3;
  }
  float* o = part + ((size_t)(b * 16 + ch)) * 520;
  o[4 + tid] = (a0a + a0b) + (a0c + a0d);
  o[4 + 256 + tid] = (a1a + a1b) + (a1c + a1d);
}

// reconcile partials -> rowscale + pooled -> logits -> top-2 routing (fused)
__global__ void route_kernel(const float* __restrict__ part, const float* __restrict__ scores,
                             const float* __restrict__ Wv, const float* __restrict__ Wmlp,
                             const float* __restrict__ alpha, float* __restrict__ allowed,
                             float* __restrict__ rowscale,
                             int* __restrict__ selE, float* __restrict__ selW, int step) {
  __shared__ float xs[512];
  __shared__ float phalf[256];
  __shared__ float pooled[128];
  __shared__ float lg[4];
  __shared__ float Msh[2], iZsh[2];
  __shared__ float cs[2][16];
  int b = blockIdx.x, tid = threadIdx.x;
  if (tid < 2) {
    float m = -1e30f;
    for (int ch = 0; ch < 16; ++ch)
      m = fmaxf(m, part[((size_t)(b * 16 + ch)) * 520 + tid]);
    float z = 0.f;
    for (int ch = 0; ch < 16; ++ch) {
      const float* p = part + ((size_t)(b * 16 + ch)) * 520;
      z += expf(p[tid] - m) * p[2 + tid];
    }
    Msh[tid] = m;
    iZsh[tid] = 1.f / z;
  }
  __syncthreads();
  if (tid < 32) {
    int n = tid >> 4, ch = tid & 15;
    cs[n][ch] = expf(part[((size_t)(b * 16 + ch)) * 520 + n] - Msh[n]);
  }
  float M0 = Msh[0], M1 = Msh[1], iZ0 = iZsh[0], iZ1 = iZsh[1];
  {
    float al = alpha[0];
    float a = (al > 20.f) ? al : log1pf(expf(al));
    float k = 0.5f * 1024.f * a;
    for (int i = tid; i < 1024; i += 256) {
      float d0 = scores[((size_t)b * 2 + 0) * 1024 + i];
      float d1 = scores[((size_t)b * 2 + 1) * 1024 + i];
      rowscale[(size_t)b * 1024 + i] = 1.f + k * (expf(d0 - M0) * iZ0 + expf(d1 - M1) * iZ1);
    }
  }
  __syncthreads();
#pragma unroll
  for (int i = 0; i < 2; ++i) {
    int id = tid + i * 256;
    int n = id >> 8, c = id & 255;
    float s = 0.f;
    for (int ch = 0; ch < 16; ++ch)
      s += cs[n][ch] * part[((size_t)(b * 16 + ch)) * 520 + 4 + n * 256 + c];
    xs[id] = s * iZsh[n];
  }
  __syncthreads();
  {
    int d = tid & 127, half = tid >> 7;
    int n = d >> 6;
    const float* xr = xs + n * 256 + half * 128;
    const float* wv = Wv + (size_t)half * 128 * 128 + d;
    float s = 0.f;
#pragma unroll 4
    for (int c = 0; c < 128; ++c) s += xr[c] * wv[(size_t)c * 128];
    phalf[tid] = s;
  }
  __syncthreads();
  if (tid < 128) pooled[tid] = phalf[tid] + phalf[tid + 128];
  __syncthreads();
  if (tid < 4) {
    float s = 0.f;
    for (int d = 0; d < 128; ++d) s += pooled[d] * Wmlp[d * 4 + tid];
    lg[tid] = s;
  }
  __syncthreads();
  if (tid == 0) {
    float al[KK];
    if (step == 0) { for (int k = 0; k < KK; ++k) al[k] = 1.f; }
    else           { for (int k = 0; k < KK; ++k) al[k] = allowed[b * KK + k]; }
    float ml[KK];
    for (int k = 0; k < KK; ++k)
      ml[k] = (al[k] > 0.5f) ? lg[k] * (1.f / 1.5f) : (-1e9f) * (1.f / 1.5f);
    float m = ml[0];
    for (int k = 1; k < KK; ++k) m = fmaxf(m, ml[k]);
    float e[KK], ssum = 0.f;
    for (int k = 0; k < KK; ++k) { e[k] = expf(ml[k] - m); ssum += e[k]; }
    float w[KK];
    for (int k = 0; k < KK; ++k) w[k] = e[k] / ssum;
    int i0 = 0;
    for (int k = 1; k < KK; ++k) if (w[k] > w[i0]) i0 = k;
    int i1 = -1;
    for (int k = 0; k < KK; ++k) {
      if (k == i0) continue;
      if (i1 < 0 || w[k] > w[i1]) i1 = k;
    }
    float denom = w[i0] + w[i1] + 1e-9f;
    selE[b * 2 + 0] = i0;
    selE[b * 2 + 1] = i1;
    selW[b * 2 + 0] = w[i0] / denom;
    selW[b * 2 + 1] = w[i1] / denom;
    if (i0 != KK - 1) al[i0] = fminf(fmaxf(al[i0] - 1.f, 0.f), 1.f);
    al[KK - 1] = fmaxf(al[KK - 1], 1.f);
    for (int k = 0; k < KK; ++k) allowed[b * KK + k] = al[k];
  }
}

// MFMA implicit-GEMM conv, single-f16. Block = 256 thr (4 waves, 2m x 2n),
// M=128 pixels, N=128 cos; wave tile 64x64. x (f16) double-buffered in
// XOR-swizzled LDS. B: register-staged from per-EXPERT f16 tables with
// in-register pk_fma combine (w0*We0 + w1*We1), ds_write to swizzled LDS,
// 3-tile group buffers (double-buffered). One barrier per 3-tap group.
__global__ __launch_bounds__(256, 2) void conv_kernel(
    const float* __restrict__ xin, const float* __restrict__ rowscale,
    const unsigned short* __restrict__ Wt,
    const float* __restrict__ be,
    const int* __restrict__ selE, const float* __restrict__ selW,
    float* __restrict__ out) {
  __shared__ __align__(16) unsigned char xsB[2][NCELL * 64];  // 2 x 13056
  __shared__ __align__(16) unsigned char BsB[2][3 * 8192];    // 2 x 24576
  __shared__ float rs_lds[NCELL];                             // 816 B

  int bid = blockIdx.x;
  int xcd = bid & 7, t2b = bid >> 3;
  int mt = t2b & 7, gs = t2b >> 3;
  int g = gs * 8 + xcd;           // (b,nt) group; its 8 mt-blocks share one XCD
  int b = g >> 1, nt = g & 1;
  int h0 = mt * 4;
  int tid = threadIdx.x;
  int lane = tid & 63, wid = tid >> 6;
  int wm = wid >> 1, wn = wid & 1;
  int l15 = lane & 15, kl = lane >> 4;

  int e0 = selE[b * 2], e1 = selE[b * 2 + 1];
  float w0 = selW[b * 2], w1 = selW[b * 2 + 1];
  fp16x2 w0h = {(__fp16)w0, (__fp16)w0};
  fp16x2 w1h = {(__fp16)w1, (__fp16)w1};
  const unsigned short* W0 = Wt + (size_t)e0 * 72 * 8192;
  const unsigned short* W1 = Wt + (size_t)e1 * 72 * 8192;

  int cellb[4];
#pragma unroll
  for (int mf = 0; mf < 4; ++mf) {
    int p0 = wm * 64 + mf * 16;
    cellb[mf] = (p0 >> 5) * XC + (p0 & 31) + l15;
  }
  int bbyte[4];
#pragma unroll
  for (int nf = 0; nf < 4; ++nf) {
    int co = wn * 64 + nf * 16 + l15;
    bbyte[nf] = (co * 64 + kl * 16) ^ ((co & 7) << 4);
  }
  // reg-stage slot mapping: slot u = tid + s2*256 of a tile-half;
  // col = u>>2 (0..127), q = u&3; global off = (nt*128+col)*32 + q*8
  int scol[2], sq[2], sdst[2];
#pragma unroll
  for (int s2 = 0; s2 < 2; ++s2) {
    int u = tid + s2 * 256;
    scol[s2] = u >> 2;
    sq[s2] = u & 3;
    sdst[s2] = (scol[s2] * 64 + sq[s2] * 16) ^ ((scol[s2] & 7) << 4);
  }

  float bias[4];
#pragma unroll
  for (int nf = 0; nf < 4; ++nf) {
    int con = nt * 128 + wn * 64 + nf * 16 + l15;
    bias[nf] = w0 * be[e0 * 256 + con] + w1 * be[e1 * 256 + con];
  }

  f32x4 acc[4][4];
#pragma unroll
  for (int mf = 0; mf < 4; ++mf)
#pragma unroll
    for (int nf = 0; nf < 4; ++nf) acc[mf][nf] = (f32x4){0.f, 0.f, 0.f, 0.f};

  for (int i = tid; i < NCELL; i += 256) {
    int r = i / XC, c = i - r * XC;
    int gr = h0 - 1 + r, gc = c - 1;
    float v = 0.f;
    if (gr >= 0 && gr < 32 && gc >= 0 && gc < 32)
      v = rowscale[(size_t)b * 1024 + gr * 32 + gc];
    rs_lds[i] = v;
  }

  auto stage_x = [&](int kcc) {
    unsigned char* xd = xsB[kcc & 1];
    for (int idx = tid; idx < NCELL * 2; idx += 256) {
      int hk = (idx >= NCELL) ? 1 : 0;
      int cell = idx - hk * NCELL;
      int r = cell / XC, c = cell - r * XC;
      int gr = h0 - 1 + r, gc = c - 1;
      uint4 pk = make_uint4(0, 0, 0, 0), pk2 = make_uint4(0, 0, 0, 0);
      if (gr >= 0 && gr < 32 && gc >= 0 && gc < 32) {
        const float* src = xin + (((size_t)b * 32 + gr) * 32 + gc) * 256 + kcc * 32 + hk * 16;
        float sc = rs_lds[cell];
        float xv[16];
        *(float4*)(xv + 0) = *(const float4*)(src + 0);
        *(float4*)(xv + 4) = *(const float4*)(src + 4);
        *(float4*)(xv + 8) = *(const float4*)(src + 8);
        *(float4*)(xv + 12) = *(const float4*)(src + 12);
        unsigned int u[8];
#pragma unroll
        for (int e2 = 0; e2 < 8; ++e2)
          u[e2] = pk2h(xv[e2 * 2] * sc, xv[e2 * 2 + 1] * sc);
        pk = make_uint4(u[0], u[1], u[2], u[3]);
        pk2 = make_uint4(u[4], u[5], u[6], u[7]);
      }
      int sx = (cell & 7) << 4;
      int b0 = (cell * 64 + hk * 32) ^ sx;
      int b1 = (cell * 64 + hk * 32 + 16) ^ sx;
      *(uint4*)(xd + b0) = pk;
      *(uint4*)(xd + b1) = pk2;
    }
  };

  // load group: 3 tiles x 2 slots x 2 experts -> 12 uint4 in regs
  auto load_group = [&](int kcA, int subBase, uint4* A, uint4* B) {
#pragma unroll
    for (int t = 0; t < 3; ++t) {
      size_t toff = (size_t)((subBase + t) * 8 + kcA) * 8192;
#pragma unroll
      for (int s2 = 0; s2 < 2; ++s2) {
        size_t off = toff + (size_t)(nt * 128 + scol[s2]) * 32 + sq[s2] * 8;
        A[t * 2 + s2] = *(const uint4*)(W0 + off);
        B[t * 2 + s2] = *(const uint4*)(W1 + off);
      }
    }
    SCHED0;
  };

  auto cmb = [&](unsigned int a, unsigned int bq) -> unsigned int {
    fp16x2 ha = __builtin_bit_cast(fp16x2, a);
    fp16x2 hb = __builtin_bit_cast(fp16x2, bq);
    fp16x2 hc = ha * w0h + hb * w1h;
    return __builtin_bit_cast(unsigned int, hc);
  };
  auto combine_write = [&](int buf, const uint4* A, const uint4* B) {
#pragma unroll
    for (int t = 0; t < 3; ++t)
#pragma unroll
      for (int s2 = 0; s2 < 2; ++s2) {
        uint4 a = A[t * 2 + s2], bq = B[t * 2 + s2], r;
        r.x = cmb(a.x, bq.x);
        r.y = cmb(a.y, bq.y);
        r.z = cmb(a.z, bq.z);
        r.w = cmb(a.w, bq.w);
        *(uint4*)(&BsB[buf][t * 8192 + sdst[s2]]) = r;
      }
  };

  auto do_tap = [&](int tap, int tIdx, const unsigned char* xsCur, int buf) {
    const int dy = (tap >= 6) ? 2 : ((tap >= 3) ? 1 : 0);
    const int dx = tap - dy * 3;
    const int dcell = dy * XC + dx;
    const unsigned char* bp = &BsB[buf][tIdx * 8192];
    f16x8 af[4], bf[4];
#pragma unroll
    for (int mf = 0; mf < 4; ++mf) {
      int cell = cellb[mf] + dcell;
      int abyte = (cell * 64 + kl * 16) ^ ((cell & 7) << 4);
      af[mf] = *(const f16x8*)(xsCur + abyte);
    }
#pragma unroll
    for (int nf = 0; nf < 4; ++nf) bf[nf] = *(const f16x8*)(bp + bbyte[nf]);
    __builtin_amdgcn_s_setprio(1);
#pragma unroll
    for (int mf = 0; mf < 4; ++mf)
#pragma unroll
      for (int nf = 0; nf < 4; ++nf)
        acc[mf][nf] = __builtin_amdgcn_mfma_f32_16x16x32_f16(af[mf], bf[nf], acc[mf][nf], 0, 0, 0);
    __builtin_amdgcn_s_setprio(0);
  };

  // ---- prologue: group (kc0, taps 0-2) into buf 0 ----
  uint4 LA[6], LB[6];
  load_group(0, 0, LA, LB);
  __syncthreads();   // rs_lds ready
  stage_x(0);
  S_VMCNT0;
  SCHED0;
  combine_write(0, LA, LB);
  S_LGKM0;
  SCHED0;
  __builtin_amdgcn_s_barrier();

#pragma unroll 1
  for (int kc = 0; kc < 8; ++kc) {
    const unsigned char* xsCur = xsB[kc & 1];
    const int bX = kc & 1;
    // group 0: taps 0-2 from BsB[bX]; prefetch group1 -> bX^1; stage next x
    if (kc < 7) stage_x(kc + 1);
    load_group(kc, 3, LA, LB);
    do_tap(0, 0, xsCur, bX);
    do_tap(1, 1, xsCur, bX);
    do_tap(2, 2, xsCur, bX);
    S_VMCNT0;
    SCHED0;
    combine_write(bX ^ 1, LA, LB);
    S_LGKM0;
    SCHED0;
    __builtin_amdgcn_s_barrier();
    // group 1: taps 3-5 from BsB[bX^1]; prefetch group2 -> bX
    load_group(kc, 6, LA, LB);
    do_tap(3, 0, xsCur, bX ^ 1);
    do_tap(4, 1, xsCur, bX ^ 1);
    do_tap(5, 2, xsCur, bX ^ 1);
    S_VMCNT0;
    SCHED0;
    combine_write(bX, LA, LB);
    S_LGKM0;
    SCHED0;
    __builtin_amdgcn_s_barrier();
    // group 2: taps 6-8 from BsB[bX]; prefetch next-kc group0 -> bX^1
    if (kc < 7) load_group(kc + 1, 0, LA, LB);
    do_tap(6, 0, xsCur, bX);
    do_tap(7, 1, xsCur, bX);
    do_tap(8, 2, xsCur, bX);
    if (kc < 7) {
      S_VMCNT0;
      SCHED0;
      combine_write(bX ^ 1, LA, LB);
      S_LGKM0;
      SCHED0;
    }
    __builtin_amdgcn_s_barrier();
  }

#pragma unroll
  for (int mf = 0; mf < 4; ++mf) {
    int p0 = wm * 64 + mf * 16;
    int pr = p0 >> 5, pc = p0 & 31;
    size_t rowbase = ((size_t)b * 32 + h0 + pr) * 32;
#pragma unroll
    for (int nf = 0; nf < 4; ++nf) {
      int co = nt * 128 + wn * 64 + nf * 16 + l15;
#pragma unroll
      for (int rr = 0; rr < 4; ++rr) {
        int col = pc + kl * 4 + rr;
        out[(rowbase + col) * 256 + co] = acc[mf][nf][rr] + bias[nf];
      }
    }
  }
}

extern "C" void kernel_launch(void* const* d_in, const int* in_sizes, int n_in,
                              void* d_out, int out_size, void* d_ws, size_t ws_size,
                              hipStream_t stream) {
  const float* x_in  = (const float*)d_in[0];
  const float* q     = (const float*)d_in[1];
  const float* Wk    = (const float*)d_in[2];
  const float* Wv    = (const float*)d_in[3];
  const float* Wmlp  = (const float*)d_in[4];
  const float* alpha = (const float*)d_in[5];
  const float* We    = (const float*)d_in[6];
  const float* be    = (const float*)d_in[7];
  float* out = (float*)d_out;
  float* ws = (float*)d_ws;

  float* qk       = ws;                  // 512
  float* scores   = qk + 512;            // 65536
  float* rowscale = scores + 65536;      // 32768
  float* part     = rowscale + 32768;    // 32*16*520 = 266240
  float* allowed  = part + 266240;       // 128
  float* selW     = allowed + 128;       // 64
  int*   selE     = (int*)(selW + 64);   // 64
  float* xbuf     = selW + 128;          // 8388608 floats
  unsigned short* Wt = (unsigned short*)(xbuf + 8388608);  // 4*72*8192 = 2,359,296 ushorts

  qk_kernel<<<2, 256, 0, stream>>>(Wk, q, qk);
  prep_w_kernel<<<dim3(72, 4), 256, 0, stream>>>(We, Wt);

  const float* step_in[3] = {x_in, out, xbuf};
  float* step_out[3] = {out, xbuf, out};

  for (int t = 0; t < 3; ++t) {
    const float* xc = step_in[t];
    poolpart_kernel<<<dim3(16, 32), 256, 0, stream>>>(xc, qk, scores, part);
    route_kernel<<<32, 256, 0, stream>>>(part, scores, Wv, Wmlp, alpha, allowed, rowscale, selE, selW, t);
    conv_kernel<<<512, 256, 0, stream>>>(xc, rowscale, Wt, be, selE, selW, step_out[t]);
  }
}